// Round 6
// baseline (759.840 us; speedup 1.0000x reference)
//
#include <hip/hip_runtime.h>
#include <hip/hip_bf16.h>

typedef short short8 __attribute__((ext_vector_type(8)));
typedef float f32x4 __attribute__((ext_vector_type(4)));

#define AS1(p) ((const __attribute__((address_space(1))) void*)(p))
#define AS3(p) ((__attribute__((address_space(3))) void*)(p))

__device__ __forceinline__ ushort f2bf(float f) {
  __hip_bfloat16 h = __float2bfloat16(f);
  return *reinterpret_cast<const ushort*>(&h);
}
__device__ __forceinline__ float bfu2f(ushort u) {
  unsigned int x = ((unsigned int)u) << 16;
  float f;
  __builtin_memcpy(&f, &x, 4);
  return f;
}
__device__ __forceinline__ float silu_f(float v) { return v / (1.f + __expf(-v)); }

// ---------------- LayerNorm fp32-in -> bf16 out (stem, D = NV*1024) --------
template<int NV>
__global__ __launch_bounds__(256) void ln_bf16_k(
    const float* __restrict__ in, const float* __restrict__ sc,
    const float* __restrict__ bi, ushort* __restrict__ out)
{
  const int D = NV * 1024;
  const long row = blockIdx.x;
  const int tx = threadIdx.x;
  const float* p = in + row * (long)D;
  float4 v[NV];
  float s = 0.f, s2 = 0.f;
#pragma unroll
  for (int t = 0; t < NV; ++t) {
    v[t] = *reinterpret_cast<const float4*>(p + t * 1024 + tx * 4);
    s  += v[t].x + v[t].y + v[t].z + v[t].w;
    s2 += v[t].x * v[t].x + v[t].y * v[t].y + v[t].z * v[t].z + v[t].w * v[t].w;
  }
#pragma unroll
  for (int o = 1; o < 64; o <<= 1) { s += __shfl_xor(s, o); s2 += __shfl_xor(s2, o); }
  __shared__ float red[2][4];
  const int wave = tx >> 6;
  if ((tx & 63) == 0) { red[0][wave] = s; red[1][wave] = s2; }
  __syncthreads();
  s  = red[0][0] + red[0][1] + red[0][2] + red[0][3];
  s2 = red[1][0] + red[1][1] + red[1][2] + red[1][3];
  const float mu   = s / D;
  const float rstd = rsqrtf(s2 / D - mu * mu + 1e-6f);
#pragma unroll
  for (int t = 0; t < NV; ++t) {
    const int d = t * 1024 + tx * 4;
    float4 g = *reinterpret_cast<const float4*>(sc + d);
    float4 b = *reinterpret_cast<const float4*>(bi + d);
    ushort4 o;
    o.x = f2bf((v[t].x - mu) * rstd * g.x + b.x);
    o.y = f2bf((v[t].y - mu) * rstd * g.y + b.y);
    o.z = f2bf((v[t].z - mu) * rstd * g.z + b.z);
    o.w = f2bf((v[t].w - mu) * rstd * g.w + b.w);
    *reinterpret_cast<ushort4*>(out + row * (long)D + d) = o;
  }
}

// ---------------- LayerNorm bf16-in -> bf16 out (D = 2048) ------------------
__global__ __launch_bounds__(256) void ln_bf16b_k(
    const ushort* __restrict__ in, const float* __restrict__ sc,
    const float* __restrict__ bi, ushort* __restrict__ out)
{
  const long row = blockIdx.x;
  const int tx = threadIdx.x;
  const int d = tx * 8;
  short8 v8 = *reinterpret_cast<const short8*>(in + row * 2048 + d);
  float v[8];
  float s = 0.f, s2 = 0.f;
#pragma unroll
  for (int j = 0; j < 8; ++j) {
    v[j] = bfu2f((ushort)v8[j]);
    s += v[j]; s2 += v[j] * v[j];
  }
#pragma unroll
  for (int o = 1; o < 64; o <<= 1) { s += __shfl_xor(s, o); s2 += __shfl_xor(s2, o); }
  __shared__ float red[2][4];
  const int wave = tx >> 6;
  if ((tx & 63) == 0) { red[0][wave] = s; red[1][wave] = s2; }
  __syncthreads();
  s  = red[0][0] + red[0][1] + red[0][2] + red[0][3];
  s2 = red[1][0] + red[1][1] + red[1][2] + red[1][3];
  const float mu   = s * (1.f / 2048.f);
  const float rstd = rsqrtf(s2 * (1.f / 2048.f) - mu * mu + 1e-6f);
  float4 g0 = *reinterpret_cast<const float4*>(sc + d);
  float4 g1 = *reinterpret_cast<const float4*>(sc + d + 4);
  float4 b0 = *reinterpret_cast<const float4*>(bi + d);
  float4 b1 = *reinterpret_cast<const float4*>(bi + d + 4);
  const float gg[8] = {g0.x, g0.y, g0.z, g0.w, g1.x, g1.y, g1.z, g1.w};
  const float bb[8] = {b0.x, b0.y, b0.z, b0.w, b1.x, b1.y, b1.z, b1.w};
  short8 o8;
#pragma unroll
  for (int j = 0; j < 8; ++j)
    o8[j] = (short)f2bf((v[j] - mu) * rstd * gg[j] + bb[j]);
  *reinterpret_cast<short8*>(out + row * 2048 + d) = o8;
}

// ---------------- fp32 [K][N] -> bf16 [N][K] (transpose + convert) ----------
__global__ __launch_bounds__(256) void transpose_bf16_k(
    const float* __restrict__ in, ushort* __restrict__ out, int K, int N)
{
  __shared__ float tile[64][65];
  const int k0 = blockIdx.y * 64, n0 = blockIdx.x * 64;
  const int tx = threadIdx.x, ty = threadIdx.y;
#pragma unroll
  for (int r = ty; r < 64; r += 4)
    tile[r][tx] = in[(long)(k0 + r) * N + n0 + tx];
  __syncthreads();
#pragma unroll
  for (int r = ty; r < 64; r += 4)
    out[(long)(n0 + r) * K + k0 + tx] = f2bf(tile[tx][r]);
}

// ============================================================================
// 256x256 GEMM — 8-phase schedule with WAR-safe staging.
// Per tile t (buffer DB = t&1), phases P1..P4:
//   P1: read af(MH0,ks0) + BOTH bf k-slices (12 ds_read); stage A(t+1)h0+h1
//       (into DB^1: its reads drained at t-1 P4)        | bar|lgkm|MFMA16|bar
//   P2: read af(MH1,ks0); stage B(t+2)h0 (into DB: B reads drained at P1)
//   P3: read af(MH0,ks1); stage B(t+2)h1
//   P4: read af(MH1,ks1); no stage; vmcnt(4) after MFMA (keeps B(t+2) only;
//       drains A(t+1)+B(t+1) needed next tile)
// Every stage issues after a barrier following the drain of the last read of
// its destination region -> no LDS WAR race.  512 thr = 8 waves (2Mx4N),
// per-wave 128x64, BK=64, LDS 128 KiB XOR-swizzled ((row&7)<<4).
// MODE 0: h=silu(acc+b) bf16; MODE 1: h+=silu(acc+b) bf16; MODE 2: C=acc+b f32.
// ============================================================================
#define STG(gsrc, ldst)                                                          \
  __builtin_amdgcn_global_load_lds(AS1(gsrc),          AS3(ldst),          16, 0, 0); \
  __builtin_amdgcn_global_load_lds(AS1((gsrc) + offQ), AS3((ldst) + 8192), 16, 0, 0)

#define ldsA(B, H) (ldsW + (B) * 65536 + (H) * 16384)
#define ldsB(B, H) (ldsW + (B) * 65536 + 32768 + (H) * 16384)

#define RD_AF(DB, MH, KS)                                                       \
  _Pragma("unroll") for (int i_ = 0; i_ < 4; ++i_)                              \
    af[i_] = *(const short8*)(smem + (DB) * 65536 + aOff + ((MH) * 4 + i_) * 2048 + rdk[(KS)])

#define RD_BF(DST, DB, KS)                                                      \
  _Pragma("unroll") for (int j_ = 0; j_ < 4; ++j_)                              \
    DST[j_] = *(const short8*)(smem + (DB) * 65536 + bOff + j_ * 2048 + rdk[(KS)])

#define MFMA16(MH, BFR)                                                         \
  _Pragma("unroll") for (int i_ = 0; i_ < 4; ++i_)                              \
  _Pragma("unroll") for (int j_ = 0; j_ < 4; ++j_)                              \
    acc[(MH) * 4 + i_][j_] = __builtin_amdgcn_mfma_f32_16x16x32_bf16(           \
        af[i_], BFR[j_], acc[(MH) * 4 + i_][j_], 0, 0, 0)

#define BARRIER __builtin_amdgcn_s_barrier()
#define LGKM0 do { asm volatile("s_waitcnt lgkmcnt(0)");                        \
                   __builtin_amdgcn_sched_barrier(0); } while (0)
#define W4 do { asm volatile("s_waitcnt vmcnt(4)" ::: "memory");                \
                __builtin_amdgcn_sched_barrier(0); } while (0)
#define W0 do { asm volatile("s_waitcnt vmcnt(0)" ::: "memory");                \
                __builtin_amdgcn_sched_barrier(0); } while (0)
#define WN do {} while (0)

// One K-tile. S1: stage A(t+1) at aP+(AO). S2: stage B(t+2) at bP+(BO).
#define DO_TILE(DB, S1, AO, S2, BO, WAITE)                                      \
  RD_AF(DB, 0, 0);                                                              \
  RD_BF(bf0, DB, 0);                                                            \
  RD_BF(bf1, DB, 1);                                                            \
  if (S1) { STG(aP + (AO), ldsA((DB) ^ 1, 0));                                  \
            STG(aP + (AO) + offH, ldsA((DB) ^ 1, 1)); }                         \
  BARRIER; LGKM0;                                                               \
  __builtin_amdgcn_s_setprio(1); MFMA16(0, bf0); __builtin_amdgcn_s_setprio(0); \
  BARRIER;                                                                      \
  RD_AF(DB, 1, 0);                                                              \
  if (S2) { STG(bP + (BO), ldsB(DB, 0)); }                                      \
  BARRIER; LGKM0;                                                               \
  __builtin_amdgcn_s_setprio(1); MFMA16(1, bf0); __builtin_amdgcn_s_setprio(0); \
  BARRIER;                                                                      \
  RD_AF(DB, 0, 1);                                                              \
  if (S2) { STG(bP + (BO) + offH, ldsB(DB, 1)); }                               \
  BARRIER; LGKM0;                                                               \
  __builtin_amdgcn_s_setprio(1); MFMA16(0, bf1); __builtin_amdgcn_s_setprio(0); \
  BARRIER;                                                                      \
  RD_AF(DB, 1, 1);                                                              \
  BARRIER; LGKM0;                                                               \
  __builtin_amdgcn_s_setprio(1); MFMA16(1, bf1); __builtin_amdgcn_s_setprio(0); \
  WAITE;                                                                        \
  BARRIER;

template<int MODE>
__global__ __launch_bounds__(512, 2) void gemm256_k(
    const ushort* __restrict__ A, const ushort* __restrict__ Bt,
    const float* __restrict__ bias, void* __restrict__ Cv,
    int M, int N, int K)
{
  extern __shared__ char smem[];
  const int tid = threadIdx.x;
  const int lane = tid & 63, wid = tid >> 6;
  const int wr = wid >> 2, wc = wid & 3;
  const int nbx = N >> 8;

  // bijective XCD swizzle (grid % 8 == 0 for all shapes here)
  int bid;
  {
    const int b = blockIdx.x;
    const int cpx = gridDim.x >> 3;
    bid = (b & 7) * cpx + (b >> 3);
  }
  const int bx = bid % nbx, by = bid / nbx;
  const long m0 = (long)by << 8, n0 = (long)bx << 8;

  // staging: thread -> (row tid>>3 [+64], inverse-swizzled 16B chunk)
  const int srow = tid >> 3;
  const int scol = (((tid & 7) * 16) ^ (((tid >> 3) & 7) << 4)) >> 1;  // elements
  const ushort* aP = A  + (m0 + srow) * (long)K + scol;
  const ushort* bP = Bt + (n0 + srow) * (long)K + scol;
  const long offH = 128L * K, offQ = 64L * K;
  char* ldsW = smem + wid * 1024;

  // ds_read offsets (bytes); XOR swizzle ((row&7)<<4) == ((lane&7)<<4)
  int rdk[2];
  rdk[0] = (((lane >> 4) * 16)     ) ^ ((lane & 7) << 4);
  rdk[1] = (((lane >> 4) * 16) + 64) ^ ((lane & 7) << 4);
  const int aOff = wr * 16384 + (lane & 15) * 128;
  const int bOff = 32768 + (wc >> 1) * 16384 + ((wc & 1) * 64 + (lane & 15)) * 128;

  f32x4 acc[8][4] = {};
  const int NT = K >> 6;  // even, >= 4

  // prologue: A0h0,A0h1,B0h0,B0h1,B1h0,B1h1 (12 loads);
  // W4 drains tile 0, keeps B1 (4 loads) in flight.
  STG(aP,      ldsA(0, 0));  STG(aP + offH,      ldsA(0, 1));
  STG(bP,      ldsB(0, 0));  STG(bP + offH,      ldsB(0, 1));
  STG(bP + 64, ldsB(1, 0));  STG(bP + 64 + offH, ldsB(1, 1));
  W4;
  BARRIER;

  short8 af[4], bf0[4], bf1[4];
  // pair (t, t+1): tile t stages A(t+1)@aP+64, B(t+2)@bP+128;
  //                tile t+1 stages A(t+2)@aP+128, B(t+3)@bP+192.
  for (int t = 0; t < NT - 2; t += 2) {
    DO_TILE(0, 1,  64, 1, 128, W4)
    DO_TILE(1, 1, 128, 1, 192, W4)
    aP += 128; bP += 128;
  }
  // tail pair (NT-2, NT-1): stage only A(NT-1); drain all at NT-2 P4.
  DO_TILE(0, 1, 64, 0, 0, W0)
  DO_TILE(1, 0,  0, 0, 0, WN)

  // epilogue: C/D layout col=lane&15, row=(lane>>4)*4+reg
#pragma unroll
  for (int j = 0; j < 4; ++j) {
    const long col = n0 + wc * 64 + j * 16 + (lane & 15);
    const float bj = bias[col];
#pragma unroll
    for (int i = 0; i < 8; ++i) {
      const long rowb = m0 + wr * 128 + i * 16 + ((lane >> 4) << 2);
#pragma unroll
      for (int r = 0; r < 4; ++r) {
        const float v = acc[i][j][r] + bj;
        const long idx = (rowb + r) * N + col;
        if (MODE == 0) {
          ((ushort*)Cv)[idx] = f2bf(silu_f(v));
        } else if (MODE == 1) {
          ushort* C = (ushort*)Cv;
          C[idx] = f2bf(bfu2f(C[idx]) + silu_f(v));
        } else {
          ((float*)Cv)[idx] = v;
        }
      }
    }
  }
}

// ---------------------------------------------------------------------------
extern "C" void kernel_launch(void* const* d_in, const int* in_sizes, int n_in,
                              void* d_out, int out_size, void* d_ws, size_t ws_size,
                              hipStream_t stream) {
  const float* x     = (const float*)d_in[0];
  const float* ln1_s = (const float*)d_in[1];
  const float* ln1_b = (const float*)d_in[2];
  const float* w1    = (const float*)d_in[3];
  const float* b1    = (const float*)d_in[4];
  const float* bln_s = (const float*)d_in[5];
  const float* bln_b = (const float*)d_in[6];
  const float* bws   = (const float*)d_in[7];
  const float* bbs   = (const float*)d_in[8];
  const float* ln2_s = (const float*)d_in[9];
  const float* ln2_b = (const float*)d_in[10];
  const float* w2    = (const float*)d_in[11];
  const float* b2    = (const float*)d_in[12];
  float* out = (float*)d_out;

  const int M = 8192;
  char* ws = (char*)d_ws;
  ushort* h   = (ushort*)ws;                                  // 8192x2048 bf16 = 32MB
  ushort* Abf = (ushort*)(ws + 33554432);                     // 8192x2048 bf16 = 32MB
  ushort* wt  = (ushort*)(ws + 67108864);                     // bf16 weights^T, 56MB
  const long W1T = 0;                        // [2048][1024]
  const long BLK = 2097152;                  // 6 x [2048][2048]
  const long W2T = BLK + 6L * 4194304;       // [1024][2048]

  (void)hipFuncSetAttribute((const void*)gemm256_k<0>,
      hipFuncAttributeMaxDynamicSharedMemorySize, 131072);
  (void)hipFuncSetAttribute((const void*)gemm256_k<1>,
      hipFuncAttributeMaxDynamicSharedMemorySize, 131072);
  (void)hipFuncSetAttribute((const void*)gemm256_k<2>,
      hipFuncAttributeMaxDynamicSharedMemorySize, 131072);

  dim3 tb(64, 4);
  transpose_bf16_k<<<dim3(2048 / 64, 1024 / 64), tb, 0, stream>>>(w1, wt + W1T, 1024, 2048);
  for (int i = 0; i < 6; ++i)
    transpose_bf16_k<<<dim3(32, 32), tb, 0, stream>>>(
        bws + (long)i * 2048 * 2048, wt + BLK + (long)i * 4194304, 2048, 2048);
  transpose_bf16_k<<<dim3(1024 / 64, 2048 / 64), tb, 0, stream>>>(w2, wt + W2T, 2048, 1024);

  // stem: h = silu(LN(x) @ w1 + b1)   (h bf16)
  ln_bf16_k<1><<<M, 256, 0, stream>>>(x, ln1_s, ln1_b, Abf);
  gemm256_k<0><<<32 * 8, 512, 131072, stream>>>(Abf, wt + W1T, b1, (void*)h, M, 2048, 1024);

  // residual blocks: h = h + silu(LN(h) @ w[i] + lb[i])
  for (int i = 0; i < 6; ++i) {
    ln_bf16b_k<<<M, 256, 0, stream>>>(h, bln_s + i * 2048, bln_b + i * 2048, Abf);
    gemm256_k<1><<<32 * 8, 512, 131072, stream>>>(
        Abf, wt + BLK + (long)i * 4194304, bbs + i * 2048, (void*)h, M, 2048, 2048);
  }

  // head: out = LN(h) @ w2 + b2
  ln_bf16b_k<<<M, 256, 0, stream>>>(h, ln2_s, ln2_b, Abf);
  gemm256_k<2><<<32 * 4, 512, 131072, stream>>>(Abf, wt + W2T, b2, (void*)out, M, 1024, 2048);
}